// Round 15
// baseline (138.524 us; speedup 1.0000x reference)
//
#include <hip/hip_runtime.h>

// ---------------------------------------------------------------------------
// VisionEncoder (PASSING since R12, absmax 1.95e-3): project -> SAT -> fused
// pool/LN/GEMM2. V4 coordinate semantics (XLA reciprocal-multiply) verified.
//
// R15: gemm_u inner-loop arithmetic-intensity fix. R14 counters showed the
// 8x4 micro-tile is LDS-throughput-bound (1.5 B/FMA -> ~20.5 us of LDS pipe;
// VALUBusy 23% with FMA floor ~9 us). New: 64x128 tile, 128 threads, 8x8
// micro-tile -> 1.0 B/FMA (LDS floor ~13.7 us). Split-K=8 unchanged (688
// blocks, finer 2-wave blocks balance better). K2/K3/K4 unchanged from R14.
// ---------------------------------------------------------------------------

#define HD 128
#define SPLITK 8

__device__ __forceinline__ int decode_dim(const int* p, int fallback) {
    if (p == nullptr) return fallback;
    int vi = *p;
    if (vi >= 1 && vi <= 1000000) return vi;
    float vf = __int_as_float(vi);
    if (vf >= 1.0f && vf <= 1000000.0f) return (int)vf;
    return fallback;
}

// V4 (verified R12): trunc( fl32( fl32(x * fl32(1/W)) * n ) ), bit-exact via
// f64; optnone so no fast-math rewrite can touch it.
__attribute__((noinline, optnone))
__device__ int coord_map(int x, int W, int n) {
    double rd = 1.0 / (double)W;
    float r = (float)rd;
    double qd = (double)x * (double)r;
    float q = (float)qd;
    double pd = (double)q * (double)n;
    float p = (float)pd;
    return (int)p;
}

// ---------------------------------------------------------------------------
// K1: partial GEMM. Tile 64 rows x 128 cols, 128 threads, 8x8 micro-tile.
// K-chunk = E/8 = 128 (4 sub-tiles of 32). As padded to 68: A-staging scalar
// writes land 2 lanes/bank (free); As[kk][tr*8] stays 16B-aligned for b128.
// ---------------------------------------------------------------------------
__global__ __launch_bounds__(128) void gemm_u_kernel(
    const float* __restrict__ T, const float* __restrict__ W1,
    float* __restrict__ U, int P, int E)
{
    __shared__ float As[32][68];    // [kk][row]
    __shared__ float Bs[32][HD];    // [kk][col]

    int t  = threadIdx.x;
    int tr = t >> 4;                // 0..7 : rows tr*8 .. tr*8+7
    int tc = t & 15;                // 0..15: cols tc*8 .. tc*8+7
    int row0 = blockIdx.x * 64;
    int ks   = blockIdx.y;
    int kchunk = E >> 3;            // 128
    int kbase  = ks * kchunk;
    float* Uo = U + (size_t)ks * (size_t)P * HD;

    float acc[8][8];
#pragma unroll
    for (int r = 0; r < 8; ++r)
#pragma unroll
        for (int j = 0; j < 8; ++j) acc[r][j] = 0.f;

    int arow = t >> 1;              // 0..63
    int akq  = (t & 1) * 16;        // 0 or 16

    for (int kt = 0; kt < kchunk; kt += 32) {
        int k0 = kbase + kt;
        {   // stage A: 64B per thread, transpose into As[k][row]
            int rg = row0 + arow; if (rg >= P) rg = P - 1;
            const float* tp = T + (size_t)rg * E + k0 + akq;
#pragma unroll
            for (int q = 0; q < 4; ++q) {
                float4 v = *(const float4*)(tp + q * 4);
                As[akq + q * 4 + 0][arow] = v.x;
                As[akq + q * 4 + 1][arow] = v.y;
                As[akq + q * 4 + 2][arow] = v.z;
                As[akq + q * 4 + 3][arow] = v.w;
            }
        }
        // stage B: coalesced float4, 8 per thread
#pragma unroll
        for (int i = 0; i < 8; ++i) {
            int j = t + i * 128;            // 0..1023 float4 index
            int row = j >> 5, col4 = j & 31;
            *(float4*)&Bs[row][col4 * 4] =
                *(const float4*)&W1[(size_t)(k0 + row) * HD + col4 * 4];
        }
        __syncthreads();

#pragma unroll
        for (int kk = 0; kk < 32; ++kk) {
            float4 a0 = *(const float4*)&As[kk][tr * 8];
            float4 a1 = *(const float4*)&As[kk][tr * 8 + 4];
            float4 b0 = *(const float4*)&Bs[kk][tc * 8];
            float4 b1 = *(const float4*)&Bs[kk][tc * 8 + 4];
            float av[8] = {a0.x, a0.y, a0.z, a0.w, a1.x, a1.y, a1.z, a1.w};
            float bv[8] = {b0.x, b0.y, b0.z, b0.w, b1.x, b1.y, b1.z, b1.w};
#pragma unroll
            for (int r = 0; r < 8; ++r)
#pragma unroll
                for (int j = 0; j < 8; ++j)
                    acc[r][j] += av[r] * bv[j];
        }
        __syncthreads();
    }

#pragma unroll
    for (int r = 0; r < 8; ++r) {
        int p = row0 + tr * 8 + r;
        if (p < P) {
            float* op = Uo + (size_t)p * HD + tc * 8;
            *(float4*)op = make_float4(acc[r][0], acc[r][1], acc[r][2], acc[r][3]);
            *(float4*)(op + 4) = make_float4(acc[r][4], acc[r][5], acc[r][6], acc[r][7]);
        }
    }
}

// ---------------------------------------------------------------------------
// K2: block (y, chalf): sum SPLITK partials of row y (74 x 64ch), x-scan,
// write SAT row y+1 (+ col-0 border).
// ---------------------------------------------------------------------------
__global__ __launch_bounds__(256) void prefix_x_kernel(
    const float* __restrict__ U, float* __restrict__ S,
    int P, int npw, int nph)
{
    extern __shared__ float tile[];            // npw*64 floats
    int t = threadIdx.x;
    int y = blockIdx.x;
    int ch0 = blockIdx.y * 64;
    size_t ustride = (size_t)P * HD;
    size_t ubase = (size_t)y * npw * HD + ch0;

    int nj = npw * 16;                         // float4 groups
    for (int j = t; j < nj; j += 256) {
        int x = j >> 4, cq = (j & 15) * 4;
        size_t off = ubase + (size_t)x * HD + cq;
        float4 s = *(const float4*)(U + off);
#pragma unroll
        for (int p = 1; p < SPLITK; ++p) {
            float4 v = *(const float4*)(U + (size_t)p * ustride + off);
            s.x += v.x; s.y += v.y; s.z += v.z; s.w += v.w;
        }
        *(float4*)&tile[x * 64 + cq] = s;
    }
    __syncthreads();

    if (t < 64) {
        int c = t;
        size_t srow = (size_t)(y + 1) * (npw + 1) * HD + ch0;
        S[srow + c] = 0.f;                     // col-0 border
        float acc = 0.f;
        for (int x = 0; x < npw; ++x) {
            acc += tile[x * 64 + c];
            S[srow + (size_t)(x + 1) * HD + c] = acc;
        }
    }
}

// ---------------------------------------------------------------------------
// K3: block (x, chalf): stage column x (y=1..nph) through LDS, y-scan,
// write back (+ row-0 border).
// ---------------------------------------------------------------------------
__global__ __launch_bounds__(256) void prefix_y_kernel(
    float* __restrict__ S, int npw, int nph)
{
    extern __shared__ float tile[];            // nph*64 floats
    int t = threadIdx.x;
    int x = blockIdx.x;
    int ch0 = blockIdx.y * 64;
    size_t stride = (size_t)(npw + 1) * HD;
    size_t base = (size_t)x * HD + ch0;

    int nj = nph * 16;
    for (int j = t; j < nj; j += 256) {
        int y = j >> 4, cq = (j & 15) * 4;
        *(float4*)&tile[y * 64 + cq] =
            *(const float4*)(S + base + (size_t)(y + 1) * stride + cq);
    }
    __syncthreads();

    if (t < 64) {
        int c = t;
        S[base + c] = 0.f;                     // row-0 border
        float acc = 0.f;
        for (int y = 0; y < nph; ++y) {
            acc += tile[y * 64 + c];
            S[base + (size_t)(y + 1) * stride + c] = acc;
        }
    }
}

// ---------------------------------------------------------------------------
// K4: 16 boxes x 128 cols; parallel LN stats; fp32 out. (unchanged)
// ---------------------------------------------------------------------------
__global__ __launch_bounds__(256) void pool_proj_kernel(
    const float* __restrict__ S, const int* __restrict__ bboxes,
    const int* __restrict__ pH, const int* __restrict__ pW,
    const float* __restrict__ b1, const float* __restrict__ gamma,
    const float* __restrict__ beta, const float* __restrict__ W2,
    const float* __restrict__ b2, float* __restrict__ out,
    int Nb, int npw, int nph, int fbW, int fbH)
{
    __shared__ float hs[16][HD + 1];
    __shared__ float Bs[32][HD];
    __shared__ float red_s[16][17], red_q[16][17];
    __shared__ int   cI11[16], cI12[16], cI21[16], cI22[16];
    __shared__ float cCnt[16];
    __shared__ float mu_s[16], rs_s[16];

    int t = threadIdx.x;
    int c = t & 127;
    int rh = t >> 7;
    int row0 = blockIdx.x * 16;

    if (t < 16) {
        int b = row0 + t; if (b >= Nb) b = Nb - 1;
        int x1 = bboxes[b * 4 + 0];
        int y1 = bboxes[b * 4 + 1];
        int x2 = bboxes[b * 4 + 2];
        int y2 = bboxes[b * 4 + 3];
        int Wi = decode_dim(pW, fbW);
        int Hi = decode_dim(pH, fbH);
        int px1 = coord_map(x1, Wi, npw);
        int px2 = coord_map(x2, Wi, npw);
        int py1 = coord_map(y1, Hi, nph);
        int py2 = coord_map(y2, Hi, nph);
        px1 = min(max(px1, 0), npw - 1);
        px2 = max(px1 + 1, min(px2, npw));
        py1 = min(max(py1, 0), nph - 1);
        py2 = max(py1 + 1, min(py2, nph));
        int st = npw + 1;
        cI11[t] = (py1 * st + px1) * HD;
        cI12[t] = (py1 * st + px2) * HD;
        cI21[t] = (py2 * st + px1) * HD;
        cI22[t] = (py2 * st + px2) * HD;
        cCnt[t] = (float)((py2 - py1) * (px2 - px1));
    }
    __syncthreads();

    float bias1 = b1[c];
    float hv[8];
#pragma unroll
    for (int r = 0; r < 8; ++r) {
        int row = rh * 8 + r;
        float s = S[cI22[row] + c] - S[cI12[row] + c]
                - S[cI21[row] + c] + S[cI11[row] + c];
        hv[r] = s / cCnt[row] + bias1;
        hs[row][c] = hv[r];
    }
    __syncthreads();

    {   // parallel LN stats: 16 threads per row, 8 elements each
        int sr = t & 15;
        int sg = t >> 4;
        float ps = 0.f, pq = 0.f;
#pragma unroll
        for (int i = 0; i < 8; ++i) {
            float v = hs[sr][sg * 8 + i];
            ps += v; pq += v * v;
        }
        red_s[sr][sg] = ps; red_q[sr][sg] = pq;
    }
    __syncthreads();
    if (t < 16) {
        float s = 0.f, q = 0.f;
#pragma unroll
        for (int i = 0; i < 16; ++i) { s += red_s[t][i]; q += red_q[t][i]; }
        float m = s * (1.0f / HD);
        float v = q * (1.0f / HD) - m * m;
        mu_s[t] = m;
        rs_s[t] = rsqrtf(v + 1e-5f);
    }
    __syncthreads();

    float g = gamma[c], be = beta[c];
#pragma unroll
    for (int r = 0; r < 8; ++r) {
        int row = rh * 8 + r;
        float x = (hv[r] - mu_s[row]) * rs_s[row] * g + be;
        hs[row][c] = fmaxf(x, 0.f);
    }
    __syncthreads();

    float bias2 = b2[c];
    float acc2[8];
#pragma unroll
    for (int r = 0; r < 8; ++r) acc2[r] = bias2;
    for (int k0 = 0; k0 < HD; k0 += 32) {
#pragma unroll
        for (int i = 0; i < 16; ++i) {
            int idx = t + i * 256;
            int kk = idx >> 7, cc = idx & 127;
            Bs[kk][cc] = W2[(size_t)(k0 + kk) * HD + cc];
        }
        __syncthreads();
#pragma unroll
        for (int kk = 0; kk < 32; ++kk) {
            float bv = Bs[kk][c];
#pragma unroll
            for (int r = 0; r < 8; ++r)
                acc2[r] += hs[rh * 8 + r][k0 + kk] * bv;
        }
        __syncthreads();
    }

#pragma unroll
    for (int r = 0; r < 8; ++r) {
        int rg = row0 + rh * 8 + r;
        if (rg < Nb) out[(size_t)rg * HD + c] = acc2[r];
    }
}

extern "C" void kernel_launch(void* const* d_in, const int* in_sizes, int n_in,
                              void* d_out, int out_size, void* d_ws, size_t ws_size,
                              hipStream_t stream) {
    int iT = 0, iB = 1, iH = 2, iW = 3, iW1 = 4, ib1 = 5, ig = 6, ibe = 7,
        iW2 = 8, ib2 = 9;
    bool has_scalars = (n_in >= 10 && in_sizes[2] == 1 && in_sizes[3] == 1);
    if (!has_scalars) { iW1 = 2; ib1 = 3; ig = 4; ibe = 5; iW2 = 6; ib2 = 7; }

    const float* tokens = (const float*)d_in[iT];
    const int*   bboxes = (const int*)d_in[iB];
    const int*   pH     = has_scalars ? (const int*)d_in[iH] : nullptr;
    const int*   pW     = has_scalars ? (const int*)d_in[iW] : nullptr;
    const float* W1     = (const float*)d_in[iW1];
    const float* b1     = (const float*)d_in[ib1];
    const float* gamma  = (const float*)d_in[ig];
    const float* beta   = (const float*)d_in[ibe];
    const float* W2     = (const float*)d_in[iW2];
    const float* b2     = (const float*)d_in[ib2];
    float* out = (float*)d_out;

    int Hd = in_sizes[ib1];               // 128
    int E  = in_sizes[iW1] / Hd;          // 1024
    int Nb = in_sizes[iB] / 4;            // 4096
    int P  = in_sizes[iT] / E;            // 5476
    int npw = 1;
    while ((npw + 1) * (npw + 1) <= P) ++npw;  // 74
    int nph = P / npw;
    (void)out_size; (void)ws_size;

    // Workspace: S (2.88 MB) + 8 partial U buffers (22.4 MB) = 25.3 MB.
    float* S = (float*)d_ws;
    size_t s_elems = ((size_t)(nph + 1) * (npw + 1) * HD + 255) & ~(size_t)255;
    float* U = S + s_elems;

    int mtiles = (P + 63) / 64;
    gemm_u_kernel<<<dim3(mtiles, SPLITK), dim3(128), 0, stream>>>(
        tokens, W1, U, P, E);
    prefix_x_kernel<<<dim3(nph, 2), dim3(256), (size_t)npw * 64 * 4, stream>>>(
        U, S, P, npw, nph);
    prefix_y_kernel<<<dim3(npw + 1, 2), dim3(256), (size_t)nph * 64 * 4, stream>>>(
        S, npw, nph);
    pool_proj_kernel<<<dim3((Nb + 15) / 16), dim3(256), 0, stream>>>(
        S, bboxes, pH, pW, b1, gamma, beta, W2, b2, out, Nb, npw, nph,
        14 * npw, 14 * nph);
}